// Round 1
// baseline (425.785 us; speedup 1.0000x reference)
//
#include <hip/hip_runtime.h>
#include <math.h>

#define NN 100000
#define EE 800000
#define HH 12
#define FF 8
#define DD 96
#define NBLK_SCAN 98   // ceil(100000/1024)

// ---------------- node scores: s_src[n,h], s_trg[n,h] ----------------
__global__ __launch_bounds__(256) void k_scores(
    const float* __restrict__ x, const float* __restrict__ wsrc,
    const float* __restrict__ wtrg, float* __restrict__ s_src,
    float* __restrict__ s_trg)
{
    int tid = blockIdx.x * 256 + threadIdx.x;
    if (tid >= NN * HH) return;
    int h = tid % HH;
    int n = tid / HH;
    const float4* xp = (const float4*)(x + (size_t)n * DD + h * FF);
    float4 a = xp[0], b = xp[1];
    const float4* s4 = (const float4*)(wsrc + h * FF);
    const float4* t4 = (const float4*)(wtrg + h * FF);
    float4 sa = s4[0], sb = s4[1];
    float4 ta = t4[0], tb = t4[1];
    s_src[tid] = a.x*sa.x + a.y*sa.y + a.z*sa.z + a.w*sa.w
               + b.x*sb.x + b.y*sb.y + b.z*sb.z + b.w*sb.w;
    s_trg[tid] = a.x*ta.x + a.y*ta.y + a.z*ta.z + a.w*ta.w
               + b.x*tb.x + b.y*tb.y + b.z*tb.z + b.w*tb.w;
}

// ---------------- CSR build ----------------
__global__ __launch_bounds__(256) void k_zero(int* __restrict__ counts)
{
    int i = blockIdx.x * 256 + threadIdx.x;
    if (i < NN) counts[i] = 0;
}

__global__ __launch_bounds__(256) void k_hist(const int* __restrict__ ei,
                                              int* __restrict__ counts)
{
    int e = blockIdx.x * 256 + threadIdx.x;
    if (e >= EE) return;
    int t = ei[EE + e];
    atomicAdd(&counts[t], 1);
}

// per-1024-chunk block sums
__global__ __launch_bounds__(256) void k_scan1(const int* __restrict__ counts,
                                               int* __restrict__ bsum)
{
    __shared__ int sd[256];
    int t = threadIdx.x;
    int base = blockIdx.x * 1024 + t * 4;
    int s = 0;
    #pragma unroll
    for (int j = 0; j < 4; ++j) {
        int i = base + j;
        s += (i < NN) ? counts[i] : 0;
    }
    sd[t] = s;
    __syncthreads();
    for (int off = 128; off > 0; off >>= 1) {
        if (t < off) sd[t] += sd[t + off];
        __syncthreads();
    }
    if (t == 0) bsum[blockIdx.x] = sd[0];
}

// exclusive scan of the 98 block sums (single block)
__global__ __launch_bounds__(128) void k_scan2(const int* __restrict__ bsum,
                                               int* __restrict__ boff)
{
    __shared__ int sd[128];
    int t = threadIdx.x;
    sd[t] = (t < NBLK_SCAN) ? bsum[t] : 0;
    __syncthreads();
    for (int off = 1; off < 128; off <<= 1) {
        int u = (t >= off) ? sd[t - off] : 0;
        __syncthreads();
        sd[t] += u;
        __syncthreads();
    }
    if (t < NBLK_SCAN) boff[t] = (t == 0) ? 0 : sd[t - 1];
}

// full exclusive scan -> offsets, and init cursor = offsets
__global__ __launch_bounds__(256) void k_scan3(const int* __restrict__ counts,
                                               const int* __restrict__ boff,
                                               int* __restrict__ offsets,
                                               int* __restrict__ cursor)
{
    __shared__ int sd[256];
    int t = threadIdx.x;
    int base = blockIdx.x * 1024 + t * 4;
    int c[4];
    int s = 0;
    #pragma unroll
    for (int j = 0; j < 4; ++j) {
        int i = base + j;
        c[j] = (i < NN) ? counts[i] : 0;
        s += c[j];
    }
    sd[t] = s;
    __syncthreads();
    for (int off = 1; off < 256; off <<= 1) {
        int u = (t >= off) ? sd[t - off] : 0;
        __syncthreads();
        sd[t] += u;
        __syncthreads();
    }
    int run = boff[blockIdx.x] + ((t == 0) ? 0 : sd[t - 1]);
    #pragma unroll
    for (int j = 0; j < 4; ++j) {
        int i = base + j;
        if (i < NN) { offsets[i] = run; cursor[i] = run; }
        run += c[j];
    }
}

__global__ __launch_bounds__(256) void k_scatter(const int* __restrict__ ei,
                                                 int* __restrict__ cursor,
                                                 int* __restrict__ esrc)
{
    int e = blockIdx.x * 256 + threadIdx.x;
    if (e >= EE) return;
    int s = ei[e];
    int t = ei[EE + e];
    int pos = atomicAdd(&cursor[t], 1);
    esrc[pos] = s;
}

// ---------------- fused aggregate + segment-softmax + RMS norm ----------------
// block = 192 threads = 16 nodes x 12 heads
__global__ __launch_bounds__(192) void k_agg(
    const float* __restrict__ x, const float* __restrict__ s_src,
    const float* __restrict__ s_trg, const int* __restrict__ offsets,
    const int* __restrict__ counts, const int* __restrict__ esrc,
    const float* __restrict__ lnw, float* __restrict__ y)
{
    __shared__ float nsq[16];
    int t  = threadIdx.x;
    int ln = t / HH;
    int h  = t % HH;
    int n  = blockIdx.x * 16 + ln;
    if (t < 16) nsq[t] = 0.f;
    __syncthreads();

    float yp[8];
    bool valid = (n < NN);
    if (valid) {
        float st  = s_trg[n * HH + h];
        int beg   = offsets[n];
        int cnt   = counts[n];
        float denom = 0.f;
        float4 aa = {0.f, 0.f, 0.f, 0.f};
        float4 ab = {0.f, 0.f, 0.f, 0.f};
        for (int k = 0; k < cnt; ++k) {
            int s = esrc[beg + k];
            float sc = s_src[s * HH + h] + st;
            sc = (sc >= 0.f) ? sc : 0.2f * sc;
            float ex = __expf(sc);
            denom += ex;
            const float4* xp = (const float4*)(x + (size_t)s * DD + h * FF);
            float4 a = xp[0], b = xp[1];
            aa.x += a.x * ex; aa.y += a.y * ex; aa.z += a.z * ex; aa.w += a.w * ex;
            ab.x += b.x * ex; ab.y += b.y * ex; ab.z += b.z * ex; ab.w += b.w * ex;
        }
        float inv = 1.f / (denom + 1e-16f);
        yp[0] = aa.x * inv; yp[1] = aa.y * inv; yp[2] = aa.z * inv; yp[3] = aa.w * inv;
        yp[4] = ab.x * inv; yp[5] = ab.y * inv; yp[6] = ab.z * inv; yp[7] = ab.w * inv;
        float ss = 0.f;
        #pragma unroll
        for (int j = 0; j < 8; ++j) ss += yp[j] * yp[j];
        atomicAdd(&nsq[ln], ss);
    }
    __syncthreads();
    if (valid) {
        float scale = rsqrtf(nsq[ln] * (1.f / 96.f) + 1e-6f);
        const float4* lw = (const float4*)(lnw + h * FF);
        float4 w1 = lw[0], w2 = lw[1];
        float4 o1, o2;
        o1.x = yp[0] * scale * w1.x; o1.y = yp[1] * scale * w1.y;
        o1.z = yp[2] * scale * w1.z; o1.w = yp[3] * scale * w1.w;
        o2.x = yp[4] * scale * w2.x; o2.y = yp[5] * scale * w2.y;
        o2.z = yp[6] * scale * w2.z; o2.w = yp[7] * scale * w2.w;
        float4* yo = (float4*)(y + (size_t)n * DD + h * FF);
        yo[0] = o1; yo[1] = o2;
    }
}

// ---------------- out = x + y @ W^T ----------------
// thread = node; y row in 96 VGPRs; W read at wave-uniform addresses -> s_load
__global__ __launch_bounds__(256) void k_out(
    const float* __restrict__ x, const float* __restrict__ y,
    const float* __restrict__ w, float* __restrict__ out)
{
    int n = blockIdx.x * 256 + threadIdx.x;
    if (n >= NN) return;
    float yr[96];
    const float4* y4 = (const float4*)(y + (size_t)n * DD);
    #pragma unroll
    for (int j = 0; j < 24; ++j) {
        float4 v = y4[j];
        yr[4*j+0] = v.x; yr[4*j+1] = v.y; yr[4*j+2] = v.z; yr[4*j+3] = v.w;
    }
    const float4* x4 = (const float4*)(x + (size_t)n * DD);
    float4* o4 = (float4*)(out + (size_t)n * DD);
    for (int j = 0; j < 24; ++j) {
        float4 r = x4[j];
        float a0 = r.x, a1 = r.y, a2 = r.z, a3 = r.w;
        const float* w0 = w + (4*j+0) * DD;
        const float* w1 = w + (4*j+1) * DD;
        const float* w2 = w + (4*j+2) * DD;
        const float* w3 = w + (4*j+3) * DD;
        #pragma unroll
        for (int k = 0; k < 96; ++k) {
            float yv = yr[k];
            a0 += yv * w0[k];
            a1 += yv * w1[k];
            a2 += yv * w2[k];
            a3 += yv * w3[k];
        }
        float4 o = {a0, a1, a2, a3};
        o4[j] = o;
    }
}

extern "C" void kernel_launch(void* const* d_in, const int* in_sizes, int n_in,
                              void* d_out, int out_size, void* d_ws, size_t ws_size,
                              hipStream_t stream)
{
    const float* x    = (const float*)d_in[0];
    const int*   ei   = (const int*)d_in[1];
    const float* wprj = (const float*)d_in[2];
    const float* wsrc = (const float*)d_in[3];
    const float* wtrg = (const float*)d_in[4];
    const float* lnw  = (const float*)d_in[5];
    float* out = (float*)d_out;

    // workspace layout (total ~52.4 MB)
    float* s_src  = (float*)d_ws;
    float* s_trg  = s_src + NN * HH;
    int*   counts = (int*)(s_trg + NN * HH);
    int*   offs   = counts + NN;
    int*   cursor = offs + NN;
    int*   bsum   = cursor + NN;
    int*   boff   = bsum + 128;
    int*   esrc   = boff + 128;
    float* y      = (float*)(esrc + EE);

    k_scores<<<(NN * HH + 255) / 256, 256, 0, stream>>>(x, wsrc, wtrg, s_src, s_trg);
    k_zero<<<(NN + 255) / 256, 256, 0, stream>>>(counts);
    k_hist<<<(EE + 255) / 256, 256, 0, stream>>>(ei, counts);
    k_scan1<<<NBLK_SCAN, 256, 0, stream>>>(counts, bsum);
    k_scan2<<<1, 128, 0, stream>>>(bsum, boff);
    k_scan3<<<NBLK_SCAN, 256, 0, stream>>>(counts, boff, offs, cursor);
    k_scatter<<<(EE + 255) / 256, 256, 0, stream>>>(ei, cursor, esrc);
    k_agg<<<(NN + 15) / 16, 192, 0, stream>>>(x, s_src, s_trg, offs, counts, esrc, lnw, y);
    k_out<<<(NN + 255) / 256, 256, 0, stream>>>(x, y, wprj, out);
}

// Round 4
// 399.200 us; speedup vs baseline: 1.0666x; 1.0666x over previous
//
#include <hip/hip_runtime.h>
#include <math.h>

#define NN 100000
#define EE 800000
#define HH 12
#define FF 8
#define DD 96
#define NBLK_SCAN 98   // ceil(100000/1024)

// ---------------- node scores: s_src[n,h], s_trg[n,h] ----------------
__global__ __launch_bounds__(256) void k_scores(
    const float* __restrict__ x, const float* __restrict__ wsrc,
    const float* __restrict__ wtrg, float* __restrict__ s_src,
    float* __restrict__ s_trg)
{
    int tid = blockIdx.x * 256 + threadIdx.x;
    if (tid >= NN * HH) return;
    int h = tid % HH;
    int n = tid / HH;
    const float4* xp = (const float4*)(x + (size_t)n * DD + h * FF);
    float4 a = xp[0], b = xp[1];
    const float4* s4 = (const float4*)(wsrc + h * FF);
    const float4* t4 = (const float4*)(wtrg + h * FF);
    float4 sa = s4[0], sb = s4[1];
    float4 ta = t4[0], tb = t4[1];
    s_src[tid] = a.x*sa.x + a.y*sa.y + a.z*sa.z + a.w*sa.w
               + b.x*sb.x + b.y*sb.y + b.z*sb.z + b.w*sb.w;
    s_trg[tid] = a.x*ta.x + a.y*ta.y + a.z*ta.z + a.w*ta.w
               + b.x*tb.x + b.y*tb.y + b.z*tb.z + b.w*tb.w;
}

// ---------------- CSR build ----------------
__global__ __launch_bounds__(256) void k_zero(int* __restrict__ counts)
{
    int i = blockIdx.x * 256 + threadIdx.x;
    if (i < NN) counts[i] = 0;
}

__global__ __launch_bounds__(256) void k_hist(const int* __restrict__ ei,
                                              int* __restrict__ counts)
{
    int e = blockIdx.x * 256 + threadIdx.x;
    if (e >= EE) return;
    int t = ei[EE + e];
    atomicAdd(&counts[t], 1);
}

// per-1024-chunk block sums
__global__ __launch_bounds__(256) void k_scan1(const int* __restrict__ counts,
                                               int* __restrict__ bsum)
{
    __shared__ int sd[256];
    int t = threadIdx.x;
    int base = blockIdx.x * 1024 + t * 4;
    int s = 0;
    #pragma unroll
    for (int j = 0; j < 4; ++j) {
        int i = base + j;
        s += (i < NN) ? counts[i] : 0;
    }
    sd[t] = s;
    __syncthreads();
    for (int off = 128; off > 0; off >>= 1) {
        if (t < off) sd[t] += sd[t + off];
        __syncthreads();
    }
    if (t == 0) bsum[blockIdx.x] = sd[0];
}

// exclusive scan of the 98 block sums (single block)
__global__ __launch_bounds__(128) void k_scan2(const int* __restrict__ bsum,
                                               int* __restrict__ boff)
{
    __shared__ int sd[128];
    int t = threadIdx.x;
    sd[t] = (t < NBLK_SCAN) ? bsum[t] : 0;
    __syncthreads();
    for (int off = 1; off < 128; off <<= 1) {
        int u = (t >= off) ? sd[t - off] : 0;
        __syncthreads();
        sd[t] += u;
        __syncthreads();
    }
    if (t < NBLK_SCAN) boff[t] = (t == 0) ? 0 : sd[t - 1];
}

// full exclusive scan -> offsets, and init cursor = offsets
__global__ __launch_bounds__(256) void k_scan3(const int* __restrict__ counts,
                                               const int* __restrict__ boff,
                                               int* __restrict__ offsets,
                                               int* __restrict__ cursor)
{
    __shared__ int sd[256];
    int t = threadIdx.x;
    int base = blockIdx.x * 1024 + t * 4;
    int c[4];
    int s = 0;
    #pragma unroll
    for (int j = 0; j < 4; ++j) {
        int i = base + j;
        c[j] = (i < NN) ? counts[i] : 0;
        s += c[j];
    }
    sd[t] = s;
    __syncthreads();
    for (int off = 1; off < 256; off <<= 1) {
        int u = (t >= off) ? sd[t - off] : 0;
        __syncthreads();
        sd[t] += u;
        __syncthreads();
    }
    int run = boff[blockIdx.x] + ((t == 0) ? 0 : sd[t - 1]);
    #pragma unroll
    for (int j = 0; j < 4; ++j) {
        int i = base + j;
        if (i < NN) { offsets[i] = run; cursor[i] = run; }
        run += c[j];
    }
}

__global__ __launch_bounds__(256) void k_scatter(const int* __restrict__ ei,
                                                 int* __restrict__ cursor,
                                                 int* __restrict__ esrc)
{
    int e = blockIdx.x * 256 + threadIdx.x;
    if (e >= EE) return;
    int s = ei[e];
    int t = ei[EE + e];
    int pos = atomicAdd(&cursor[t], 1);
    esrc[pos] = s;
}

// ---------------- fused aggregate + segment-softmax + RMS norm ----------------
// block = 192 threads = 16 nodes x 12 heads
__global__ __launch_bounds__(192) void k_agg(
    const float* __restrict__ x, const float* __restrict__ s_src,
    const float* __restrict__ s_trg, const int* __restrict__ offsets,
    const int* __restrict__ counts, const int* __restrict__ esrc,
    const float* __restrict__ lnw, float* __restrict__ y)
{
    __shared__ float nsq[16];
    int t  = threadIdx.x;
    int ln = t / HH;
    int h  = t % HH;
    int n  = blockIdx.x * 16 + ln;
    if (t < 16) nsq[t] = 0.f;
    __syncthreads();

    float yp[8];
    bool valid = (n < NN);
    if (valid) {
        float st  = s_trg[n * HH + h];
        int beg   = offsets[n];
        int cnt   = counts[n];
        float denom = 0.f;
        float4 aa = {0.f, 0.f, 0.f, 0.f};
        float4 ab = {0.f, 0.f, 0.f, 0.f};
        for (int k = 0; k < cnt; ++k) {
            int s = esrc[beg + k];
            float sc = s_src[s * HH + h] + st;
            sc = (sc >= 0.f) ? sc : 0.2f * sc;
            float ex = __expf(sc);
            denom += ex;
            const float4* xp = (const float4*)(x + (size_t)s * DD + h * FF);
            float4 a = xp[0], b = xp[1];
            aa.x += a.x * ex; aa.y += a.y * ex; aa.z += a.z * ex; aa.w += a.w * ex;
            ab.x += b.x * ex; ab.y += b.y * ex; ab.z += b.z * ex; ab.w += b.w * ex;
        }
        float inv = 1.f / (denom + 1e-16f);
        yp[0] = aa.x * inv; yp[1] = aa.y * inv; yp[2] = aa.z * inv; yp[3] = aa.w * inv;
        yp[4] = ab.x * inv; yp[5] = ab.y * inv; yp[6] = ab.z * inv; yp[7] = ab.w * inv;
        float ss = 0.f;
        #pragma unroll
        for (int j = 0; j < 8; ++j) ss += yp[j] * yp[j];
        atomicAdd(&nsq[ln], ss);
    }
    __syncthreads();
    if (valid) {
        float scale = rsqrtf(nsq[ln] * (1.f / 96.f) + 1e-6f);
        const float4* lw = (const float4*)(lnw + h * FF);
        float4 w1 = lw[0], w2 = lw[1];
        float4 o1, o2;
        o1.x = yp[0] * scale * w1.x; o1.y = yp[1] * scale * w1.y;
        o1.z = yp[2] * scale * w1.z; o1.w = yp[3] * scale * w1.w;
        o2.x = yp[4] * scale * w2.x; o2.y = yp[5] * scale * w2.y;
        o2.z = yp[6] * scale * w2.z; o2.w = yp[7] * scale * w2.w;
        float4* yo = (float4*)(y + (size_t)n * DD + h * FF);
        yo[0] = o1; yo[1] = o2;
    }
}

// ---------------- out = x + y @ W^T (tiled, coalesced) ----------------
// block = 256 = 4 waves; tile = 64 nodes; grid = ceil(NN/64)
// lane = node, wave w owns cols 24w..24w+23.
// y tile staged in LDS (row pad 97 -> 2-way bank alias = free).
// W indices wave-uniform -> scalar s_load path.
// Epilogue bounces acc through LDS so out-stores are coalesced float4.
__global__ __launch_bounds__(256) void k_out(
    const float* __restrict__ x, const float* __restrict__ y,
    const float* __restrict__ w, float* __restrict__ out)
{
    __shared__ float ylds[64 * 97];
    int t  = threadIdx.x;
    int wv = t >> 6;
    int l  = t & 63;
    int tile = blockIdx.x * 64;
    int nrem = NN - tile;          // last block: 32

    // stage y tile, fully coalesced float4
    #pragma unroll
    for (int i = 0; i < 6; ++i) {
        int lin = t * 4 + i * 1024;
        int r = lin / 96;
        int c = lin - r * 96;      // multiple of 4
        if (r < nrem) {
            float4 v = *(const float4*)(y + (size_t)tile * DD + lin);
            ylds[r * 97 + c + 0] = v.x;
            ylds[r * 97 + c + 1] = v.y;
            ylds[r * 97 + c + 2] = v.z;
            ylds[r * 97 + c + 3] = v.w;
        }
    }
    __syncthreads();

    int cbase = wv * 24;
    float acc[24];
    #pragma unroll
    for (int j = 0; j < 24; ++j) acc[j] = 0.f;

    // all lanes compute (invalid lanes produce garbage, never stored)
    for (int k = 0; k < 96; k += 4) {
        float y0 = ylds[l * 97 + k + 0];
        float y1 = ylds[l * 97 + k + 1];
        float y2 = ylds[l * 97 + k + 2];
        float y3 = ylds[l * 97 + k + 3];
        #pragma unroll
        for (int j = 0; j < 24; ++j) {
            const float* wr = w + (cbase + j) * DD + k;   // wave-uniform -> s_load_dwordx4
            acc[j] += y0 * wr[0] + y1 * wr[1] + y2 * wr[2] + y3 * wr[3];
        }
    }

    __syncthreads();
    // scatter acc into LDS: addr = l*97 + c -> banks (l+c)%32, conflict-free per instr
    #pragma unroll
    for (int j = 0; j < 24; ++j)
        ylds[l * 97 + cbase + j] = acc[j];
    __syncthreads();

    // coalesced store with residual add
    #pragma unroll
    for (int i = 0; i < 6; ++i) {
        int lin = t * 4 + i * 1024;
        int r = lin / 96;
        int c = lin - r * 96;
        if (r < nrem) {
            float4 xv = *(const float4*)(x + (size_t)tile * DD + lin);
            float4 o;
            o.x = xv.x + ylds[r * 97 + c + 0];
            o.y = xv.y + ylds[r * 97 + c + 1];
            o.z = xv.z + ylds[r * 97 + c + 2];
            o.w = xv.w + ylds[r * 97 + c + 3];
            *(float4*)(out + (size_t)tile * DD + lin) = o;
        }
    }
}

extern "C" void kernel_launch(void* const* d_in, const int* in_sizes, int n_in,
                              void* d_out, int out_size, void* d_ws, size_t ws_size,
                              hipStream_t stream)
{
    const float* x    = (const float*)d_in[0];
    const int*   ei   = (const int*)d_in[1];
    const float* wprj = (const float*)d_in[2];
    const float* wsrc = (const float*)d_in[3];
    const float* wtrg = (const float*)d_in[4];
    const float* lnw  = (const float*)d_in[5];
    float* out = (float*)d_out;

    float* s_src  = (float*)d_ws;
    float* s_trg  = s_src + NN * HH;
    int*   counts = (int*)(s_trg + NN * HH);
    int*   offs   = counts + NN;
    int*   cursor = offs + NN;
    int*   bsum   = cursor + NN;
    int*   boff   = bsum + 128;
    int*   esrc   = boff + 128;
    float* y      = (float*)(esrc + EE);

    k_scores<<<(NN * HH + 255) / 256, 256, 0, stream>>>(x, wsrc, wtrg, s_src, s_trg);
    k_zero<<<(NN + 255) / 256, 256, 0, stream>>>(counts);
    k_hist<<<(EE + 255) / 256, 256, 0, stream>>>(ei, counts);
    k_scan1<<<NBLK_SCAN, 256, 0, stream>>>(counts, bsum);
    k_scan2<<<1, 128, 0, stream>>>(bsum, boff);
    k_scan3<<<NBLK_SCAN, 256, 0, stream>>>(counts, boff, offs, cursor);
    k_scatter<<<(EE + 255) / 256, 256, 0, stream>>>(ei, cursor, esrc);
    k_agg<<<(NN + 15) / 16, 192, 0, stream>>>(x, s_src, s_trg, offs, counts, esrc, lnw, y);
    k_out<<<(NN + 63) / 64, 256, 0, stream>>>(x, y, wprj, out);   // 1563 blocks of 64 nodes
}

// Round 6
// 276.030 us; speedup vs baseline: 1.5425x; 1.4462x over previous
//
#include <hip/hip_runtime.h>
#include <math.h>

#define NN 100000
#define EE 800000
#define HH 12
#define FF 8
#define DD 96
#define NBLK_SCAN 98   // ceil(100000/1024)
#define WROW 104       // padded LDS row (bf16 elems): 52 dwords -> 2-way banks on frag reads

typedef __bf16 bf16x8 __attribute__((ext_vector_type(8)));
typedef float  f32x4  __attribute__((ext_vector_type(4)));

static __device__ __forceinline__ unsigned short f2bf(float f) {
    unsigned u = __builtin_bit_cast(unsigned, f);
    u += 0x7fffu + ((u >> 16) & 1u);           // round-to-nearest-even
    return (unsigned short)(u >> 16);
}

// ---------------- node scores: s_src[n,h], s_trg[n,h] ----------------
__global__ __launch_bounds__(256) void k_scores(
    const float* __restrict__ x, const float* __restrict__ wsrc,
    const float* __restrict__ wtrg, float* __restrict__ s_src,
    float* __restrict__ s_trg)
{
    int tid = blockIdx.x * 256 + threadIdx.x;
    if (tid >= NN * HH) return;
    int h = tid % HH;
    int n = tid / HH;
    const float4* xp = (const float4*)(x + (size_t)n * DD + h * FF);
    float4 a = xp[0], b = xp[1];
    const float4* s4 = (const float4*)(wsrc + h * FF);
    const float4* t4 = (const float4*)(wtrg + h * FF);
    float4 sa = s4[0], sb = s4[1];
    float4 ta = t4[0], tb = t4[1];
    s_src[tid] = a.x*sa.x + a.y*sa.y + a.z*sa.z + a.w*sa.w
               + b.x*sb.x + b.y*sb.y + b.z*sb.z + b.w*sb.w;
    s_trg[tid] = a.x*ta.x + a.y*ta.y + a.z*ta.z + a.w*ta.w
               + b.x*tb.x + b.y*tb.y + b.z*tb.z + b.w*tb.w;
}

// ---------------- CSR build ----------------
__global__ __launch_bounds__(256) void k_zero(int* __restrict__ counts)
{
    int i = blockIdx.x * 256 + threadIdx.x;
    if (i < NN) counts[i] = 0;
}

__global__ __launch_bounds__(256) void k_hist(const int* __restrict__ ei,
                                              int* __restrict__ counts)
{
    int e = blockIdx.x * 256 + threadIdx.x;
    if (e >= EE) return;
    int t = ei[EE + e];
    atomicAdd(&counts[t], 1);
}

// per-1024-chunk block sums
__global__ __launch_bounds__(256) void k_scan1(const int* __restrict__ counts,
                                               int* __restrict__ bsum)
{
    __shared__ int sd[256];
    int t = threadIdx.x;
    int base = blockIdx.x * 1024 + t * 4;
    int s = 0;
    #pragma unroll
    for (int j = 0; j < 4; ++j) {
        int i = base + j;
        s += (i < NN) ? counts[i] : 0;
    }
    sd[t] = s;
    __syncthreads();
    for (int off = 128; off > 0; off >>= 1) {
        if (t < off) sd[t] += sd[t + off];
        __syncthreads();
    }
    if (t == 0) bsum[blockIdx.x] = sd[0];
}

// exclusive scan of the 98 block sums (single block)
__global__ __launch_bounds__(128) void k_scan2(const int* __restrict__ bsum,
                                               int* __restrict__ boff)
{
    __shared__ int sd[128];
    int t = threadIdx.x;
    sd[t] = (t < NBLK_SCAN) ? bsum[t] : 0;
    __syncthreads();
    for (int off = 1; off < 128; off <<= 1) {
        int u = (t >= off) ? sd[t - off] : 0;
        __syncthreads();
        sd[t] += u;
        __syncthreads();
    }
    if (t < NBLK_SCAN) boff[t] = (t == 0) ? 0 : sd[t - 1];
}

// full exclusive scan -> offsets, and init cursor = offsets
__global__ __launch_bounds__(256) void k_scan3(const int* __restrict__ counts,
                                               const int* __restrict__ boff,
                                               int* __restrict__ offsets,
                                               int* __restrict__ cursor)
{
    __shared__ int sd[256];
    int t = threadIdx.x;
    int base = blockIdx.x * 1024 + t * 4;
    int c[4];
    int s = 0;
    #pragma unroll
    for (int j = 0; j < 4; ++j) {
        int i = base + j;
        c[j] = (i < NN) ? counts[i] : 0;
        s += c[j];
    }
    sd[t] = s;
    __syncthreads();
    for (int off = 1; off < 256; off <<= 1) {
        int u = (t >= off) ? sd[t - off] : 0;
        __syncthreads();
        sd[t] += u;
        __syncthreads();
    }
    int run = boff[blockIdx.x] + ((t == 0) ? 0 : sd[t - 1]);
    #pragma unroll
    for (int j = 0; j < 4; ++j) {
        int i = base + j;
        if (i < NN) { offsets[i] = run; cursor[i] = run; }
        run += c[j];
    }
}

__global__ __launch_bounds__(256) void k_scatter(const int* __restrict__ ei,
                                                 int* __restrict__ cursor,
                                                 int* __restrict__ esrc)
{
    int e = blockIdx.x * 256 + threadIdx.x;
    if (e >= EE) return;
    int s = ei[e];
    int t = ei[EE + e];
    int pos = atomicAdd(&cursor[t], 1);
    esrc[pos] = s;
}

// ---------------- fused aggregate + segment-softmax + RMS norm ----------------
// block = 192 threads = 16 nodes x 12 heads
__global__ __launch_bounds__(192) void k_agg(
    const float* __restrict__ x, const float* __restrict__ s_src,
    const float* __restrict__ s_trg, const int* __restrict__ offsets,
    const int* __restrict__ counts, const int* __restrict__ esrc,
    const float* __restrict__ lnw, float* __restrict__ y)
{
    __shared__ float nsq[16];
    int t  = threadIdx.x;
    int ln = t / HH;
    int h  = t % HH;
    int n  = blockIdx.x * 16 + ln;
    if (t < 16) nsq[t] = 0.f;
    __syncthreads();

    float yp[8];
    bool valid = (n < NN);
    if (valid) {
        float st  = s_trg[n * HH + h];
        int beg   = offsets[n];
        int cnt   = counts[n];
        float denom = 0.f;
        float4 aa = {0.f, 0.f, 0.f, 0.f};
        float4 ab = {0.f, 0.f, 0.f, 0.f};
        for (int k = 0; k < cnt; ++k) {
            int s = esrc[beg + k];
            float sc = s_src[s * HH + h] + st;
            sc = (sc >= 0.f) ? sc : 0.2f * sc;
            float ex = __expf(sc);
            denom += ex;
            const float4* xp = (const float4*)(x + (size_t)s * DD + h * FF);
            float4 a = xp[0], b = xp[1];
            aa.x += a.x * ex; aa.y += a.y * ex; aa.z += a.z * ex; aa.w += a.w * ex;
            ab.x += b.x * ex; ab.y += b.y * ex; ab.z += b.z * ex; ab.w += b.w * ex;
        }
        float inv = 1.f / (denom + 1e-16f);
        yp[0] = aa.x * inv; yp[1] = aa.y * inv; yp[2] = aa.z * inv; yp[3] = aa.w * inv;
        yp[4] = ab.x * inv; yp[5] = ab.y * inv; yp[6] = ab.z * inv; yp[7] = ab.w * inv;
        float ss = 0.f;
        #pragma unroll
        for (int j = 0; j < 8; ++j) ss += yp[j] * yp[j];
        atomicAdd(&nsq[ln], ss);
    }
    __syncthreads();
    if (valid) {
        float scale = rsqrtf(nsq[ln] * (1.f / 96.f) + 1e-6f);
        const float4* lw = (const float4*)(lnw + h * FF);
        float4 w1 = lw[0], w2 = lw[1];
        float4 o1, o2;
        o1.x = yp[0] * scale * w1.x; o1.y = yp[1] * scale * w1.y;
        o1.z = yp[2] * scale * w1.z; o1.w = yp[3] * scale * w1.w;
        o2.x = yp[4] * scale * w2.x; o2.y = yp[5] * scale * w2.y;
        o2.z = yp[6] * scale * w2.z; o2.w = yp[7] * scale * w2.w;
        float4* yo = (float4*)(y + (size_t)n * DD + h * FF);
        yo[0] = o1; yo[1] = o2;
    }
}

// ---------------- out = x + y @ W^T  (bf16 MFMA) ----------------
// block = 256 = 4 waves; tile = 64 nodes; grid = ceil(NN/64).
// W (96x96) + y-tile (64x96) staged in LDS as bf16, rows padded to 104
// (52 dwords -> frag ds_read_b128 is 2-way bank alias = free).
// Wave wv computes rows wv*16..wv*16+15, all 96 cols: 3 k-steps x 6 n-frags
// of mfma_f32_16x16x32_bf16. No scalar loads in the hot loop (R4 fix: the
// s_load-of-W latency was 79% of k_out's time).
// Epilogue: acc -> f32 LDS bounce -> coalesced float4 x-add + store.
__global__ __launch_bounds__(256) void k_out(
    const float* __restrict__ x, const float* __restrict__ y,
    const float* __restrict__ w, float* __restrict__ out)
{
    __shared__ char lds_raw[(96 + 64) * WROW * 2];   // 33280 B
    unsigned short* wl = (unsigned short*)lds_raw;                  // [96][WROW]
    unsigned short* yl = ((unsigned short*)lds_raw) + 96 * WROW;    // [64][WROW]
    int t  = threadIdx.x;
    int wv = t >> 6;
    int l  = t & 63;
    int tile = blockIdx.x * 64;
    int nrem = NN - tile;          // last block: 32

    // stage W (9216 floats), coalesced float4 -> bf16
    #pragma unroll
    for (int i = 0; i < 9; ++i) {
        int lin = t * 4 + i * 1024;
        int r = lin / 96, c = lin - (lin / 96) * 96;
        float4 v = *(const float4*)(w + lin);
        unsigned short* p = wl + r * WROW + c;
        p[0] = f2bf(v.x); p[1] = f2bf(v.y); p[2] = f2bf(v.z); p[3] = f2bf(v.w);
    }
    // stage y tile (6144 floats)
    #pragma unroll
    for (int i = 0; i < 6; ++i) {
        int lin = t * 4 + i * 1024;
        int r = lin / 96, c = lin - (lin / 96) * 96;
        if (r < nrem) {
            float4 v = *(const float4*)(y + (size_t)tile * DD + lin);
            unsigned short* p = yl + r * WROW + c;
            p[0] = f2bf(v.x); p[1] = f2bf(v.y); p[2] = f2bf(v.z); p[3] = f2bf(v.w);
        }
    }
    __syncthreads();

    // MFMA: A[m][k] = y-tile, B[k][n] = W^T  (lane: A row=l&15, B col=l&15,
    // k = (l>>4)*8 + 0..7 contiguous -> both frags are 16B LDS reads)
    f32x4 acc[6] = {};
    int arow   = wv * 16 + (l & 15);
    int kchunk = (l >> 4) * 8;
    #pragma unroll
    for (int s = 0; s < 3; ++s) {
        bf16x8 af = *(const bf16x8*)(yl + arow * WROW + s * 32 + kchunk);
        #pragma unroll
        for (int nt = 0; nt < 6; ++nt) {
            bf16x8 bfr = *(const bf16x8*)(wl + (nt * 16 + (l & 15)) * WROW + s * 32 + kchunk);
            acc[nt] = __builtin_amdgcn_mfma_f32_16x16x32_bf16(af, bfr, acc[nt], 0, 0, 0);
        }
    }
    __syncthreads();

    // bounce acc through f32 LDS (C/D layout: col=lane&15, row=(lane>>4)*4+reg)
    float* fb = (float*)lds_raw;   // [64][97] = 24832 B < 33280
    #pragma unroll
    for (int nt = 0; nt < 6; ++nt) {
        #pragma unroll
        for (int r = 0; r < 4; ++r) {
            int row = wv * 16 + (l >> 4) * 4 + r;
            int col = nt * 16 + (l & 15);
            fb[row * 97 + col] = acc[nt][r];
        }
    }
    __syncthreads();

    // coalesced residual add + store
    #pragma unroll
    for (int i = 0; i < 6; ++i) {
        int lin = t * 4 + i * 1024;
        int r = lin / 96, c = lin - (lin / 96) * 96;
        if (r < nrem) {
            float4 xv = *(const float4*)(x + (size_t)tile * DD + lin);
            float4 o;
            o.x = xv.x + fb[r * 97 + c + 0];
            o.y = xv.y + fb[r * 97 + c + 1];
            o.z = xv.z + fb[r * 97 + c + 2];
            o.w = xv.w + fb[r * 97 + c + 3];
            *(float4*)(out + (size_t)tile * DD + lin) = o;
        }
    }
}

extern "C" void kernel_launch(void* const* d_in, const int* in_sizes, int n_in,
                              void* d_out, int out_size, void* d_ws, size_t ws_size,
                              hipStream_t stream)
{
    const float* x    = (const float*)d_in[0];
    const int*   ei   = (const int*)d_in[1];
    const float* wprj = (const float*)d_in[2];
    const float* wsrc = (const float*)d_in[3];
    const float* wtrg = (const float*)d_in[4];
    const float* lnw  = (const float*)d_in[5];
    float* out = (float*)d_out;

    float* s_src  = (float*)d_ws;
    float* s_trg  = s_src + NN * HH;
    int*   counts = (int*)(s_trg + NN * HH);
    int*   offs   = counts + NN;
    int*   cursor = offs + NN;
    int*   bsum   = cursor + NN;
    int*   boff   = bsum + 128;
    int*   esrc   = boff + 128;
    float* y      = (float*)(esrc + EE);

    k_scores<<<(NN * HH + 255) / 256, 256, 0, stream>>>(x, wsrc, wtrg, s_src, s_trg);
    k_zero<<<(NN + 255) / 256, 256, 0, stream>>>(counts);
    k_hist<<<(EE + 255) / 256, 256, 0, stream>>>(ei, counts);
    k_scan1<<<NBLK_SCAN, 256, 0, stream>>>(counts, bsum);
    k_scan2<<<1, 128, 0, stream>>>(bsum, boff);
    k_scan3<<<NBLK_SCAN, 256, 0, stream>>>(counts, boff, offs, cursor);
    k_scatter<<<(EE + 255) / 256, 256, 0, stream>>>(ei, cursor, esrc);
    k_agg<<<(NN + 15) / 16, 192, 0, stream>>>(x, s_src, s_trg, offs, counts, esrc, lnw, y);
    k_out<<<(NN + 63) / 64, 256, 0, stream>>>(x, y, wprj, out);
}